// Round 5
// baseline (255.634 us; speedup 1.0000x reference)
//
#include <hip/hip_runtime.h>
#include <hip/hip_bf16.h>
#include <stdint.h>

#define B_      4
#define CIN     512
#define COUT    512
#define L_      4096
#define K_      7
#define OUT_LEN 4090

typedef unsigned short ushort_t;
typedef __attribute__((ext_vector_type(8))) __bf16 bf16x8;
typedef __attribute__((ext_vector_type(4))) float f32x4;

__device__ __forceinline__ uint32_t f2bf(float f) {   // RNE float->bf16 bits
    uint32_t u = __float_as_uint(f);
    return (u + 0x7fffu + ((u >> 16) & 1u)) >> 16;
}

__device__ __forceinline__ uint32_t pack2bf(float s0, float s1) {
    __hip_bfloat162 h = __float22bfloat162_rn(make_float2(s0, s1));  // x=s0 -> low 16
    uint32_t r;
    __builtin_memcpy(&r, &h, 4);
    return r;
}

__device__ __forceinline__ void async16(const void* g, void* l) {
    __builtin_amdgcn_global_load_lds(
        (const __attribute__((address_space(1))) unsigned int*)g,
        (__attribute__((address_space(3))) unsigned int*)l, 16, 0, 0);
}

// ---------------- kernel 1: weight reorder+cast: Wr[k][d][c] bf16 ----------------
__global__ __launch_bounds__(256)
void reorder_w_kernel(const float* __restrict__ w, uint32_t* __restrict__ Wr) {
    const int e     = blockIdx.x * 256 + threadIdx.x;
    const int cpair = e & 255;
    const int rest  = e >> 8;
    const int d     = rest & 511;
    const int k     = rest >> 9;
    const int c     = cpair * 2;
    const float w0 = w[(size_t)d * 3584 + (size_t)c * 7 + k];
    const float w1 = w[(size_t)d * 3584 + (size_t)(c + 1) * 7 + k];
    Wr[((size_t)(k * 512 + d) << 8) + cpair] = (f2bf(w1) << 16) | f2bf(w0);
}

// ---------------- kernel 2: fused interp + bf16 MFMA GEMM, software-pipelined ----------------
// grid (32 o-blocks, 4 d-blocks, 4 batch), 256 threads (4 waves); 112 K-steps of 32
__global__ __launch_bounds__(256)
void fused_kernel(const float* __restrict__ x, const float* __restrict__ offs,
                  const ushort_t* __restrict__ Wr, const float* __restrict__ bias,
                  float* __restrict__ out) {
    const int o0   = blockIdx.x * 128;
    const int d0   = blockIdx.y * 128;
    const int b    = blockIdx.z;
    const int tid  = threadIdx.x;
    const int wv   = tid >> 6;
    const int lane = tid & 63;
    const int m16  = lane & 15;
    const int quad = lane >> 4;
    const int wm   = wv >> 1;
    const int wn   = wv & 1;

    __shared__ float    XT[136 * 32];                    // x slab, swizzled col-major
    __shared__ __align__(16) uint32_t Sb[2][2048];       // B-tile dbuf [128 o][16 cpair]
    __shared__ __align__(16) uint32_t Ab[2][2048];       // A-tile dbuf [128 d][32 c] bf16
    __shared__ int      SU[896];
    __shared__ float2   PG[896];

    // ---- interp params (once per block) ----
    for (int e = tid; e < 896; e += 256) {
        const int k  = e >> 7;
        const int ol = e & 127;
        int o = o0 + ol; if (o > OUT_LEN - 1) o = OUT_LEN - 1;
        const float t0  = (float)o;
        const float off = offs[((size_t)b * OUT_LEN + o) * K_ + k];
        float T = t0 + (float)k + off;
        T = fmaxf(T, t0);
        T = fminf(T, t0 + 6.0f);
        int u0 = (int)floorf(T);
        if (u0 > L_ - 2) u0 = L_ - 2;
        const float g0 = fmaxf(1.0f - fabsf((float)u0 - T), 0.0f);
        const float g1 = fmaxf(1.0f - fabsf((float)(u0 + 1) - T), 0.0f);
        SU[e] = u0 - o0;
        PG[e] = make_float2(g0, g1);
    }

    f32x4 acc[4][4];
    #pragma unroll
    for (int i = 0; i < 4; ++i) {
        #pragma unroll
        for (int j = 0; j < 4; ++j) acc[i][j] = (f32x4){0.f, 0.f, 0.f, 0.f};
    }

    const int dstage = tid >> 2;
    const int cstage = (tid & 3) * 8;
    const int olr    = tid >> 1;
    const int half   = tid & 1;

    const float* xb = x + (size_t)b * CIN * L_ + o0;

    // ---------- helpers as macros (uniform control flow) ----------
#define STAGE_XT(CC)                                                              \
    {                                                                             \
        const float* xc = xb + (size_t)(CC) * 32 * L_;                            \
        _Pragma("unroll")                                                         \
        for (int i_ = 0; i_ < 5; ++i_) {                                          \
            const int e_ = i_ * 256 + tid;                                        \
            if (e_ < 1088) {                                                      \
                const int c_    = e_ / 34;                                        \
                const int col4_ = e_ - c_ * 34;                                   \
                const int colb_ = col4_ * 4;                                      \
                float4 v_;                                                        \
                if (o0 + colb_ + 3 < L_) {                                        \
                    v_ = *(const float4*)(xc + (size_t)c_ * L_ + colb_);          \
                } else {                                                          \
                    float a0_ = (o0 + colb_ + 0 < L_) ? xc[(size_t)c_ * L_ + colb_ + 0] : 0.f; \
                    float a1_ = (o0 + colb_ + 1 < L_) ? xc[(size_t)c_ * L_ + colb_ + 1] : 0.f; \
                    float a2_ = (o0 + colb_ + 2 < L_) ? xc[(size_t)c_ * L_ + colb_ + 2] : 0.f; \
                    float a3_ = (o0 + colb_ + 3 < L_) ? xc[(size_t)c_ * L_ + colb_ + 3] : 0.f; \
                    v_ = make_float4(a0_, a1_, a2_, a3_);                         \
                }                                                                 \
                const int cp_ = c_ >> 1, h_ = c_ & 1;                             \
                const float* vf_ = (const float*)&v_;                             \
                _Pragma("unroll")                                                 \
                for (int ii_ = 0; ii_ < 4; ++ii_) {                               \
                    const int col_ = colb_ + ii_;                                 \
                    XT[col_ * 32 + (((cp_ ^ (col_ & 15)) << 1) | h_)] = vf_[ii_]; \
                }                                                                 \
            }                                                                     \
        }                                                                         \
    }

#define COMPUTE_S(KN, BUFN)                                                       \
    {                                                                             \
        const int   row_ = ((KN) << 7) | olr;                                     \
        const int   u_   = SU[row_];                                              \
        const float2 g_  = PG[row_];                                              \
        const float2* XT2_ = (const float2*)XT;                                   \
        const int base0_ = u_ * 16,  sw0_ = u_ & 15;                              \
        const int base1_ = base0_ + 16, sw1_ = (u_ + 1) & 15;                     \
        uint32_t r_[8];                                                           \
        _Pragma("unroll")                                                         \
        for (int j_ = 0; j_ < 8; ++j_) {                                          \
            const int cp_ = half * 8 + j_;                                        \
            const float2 lo_ = XT2_[base0_ + (cp_ ^ sw0_)];                       \
            const float2 hi_ = XT2_[base1_ + (cp_ ^ sw1_)];                       \
            r_[j_] = pack2bf(g_.x * lo_.x + g_.y * hi_.x,                         \
                             g_.x * lo_.y + g_.y * hi_.y);                        \
        }                                                                         \
        uint32_t* Sw_ = &Sb[BUFN][olr * 16 + half * 8];                           \
        *(uint4*)(Sw_ + 0) = make_uint4(r_[0], r_[1], r_[2], r_[3]);              \
        *(uint4*)(Sw_ + 4) = make_uint4(r_[4], r_[5], r_[6], r_[7]);              \
    }

#define ISSUE_DMA(KN, CCN, BUFN)                                                  \
    {                                                                             \
        const ushort_t* Wk_ = Wr + (size_t)((KN) * 512 + d0) * 512 + (CCN) * 32;  \
        ushort_t* Al_ = (ushort_t*)Ab[BUFN];                                      \
        async16(Wk_ + (size_t)dstage * 512 + cstage,        Al_ + wv * 512);      \
        async16(Wk_ + (size_t)(dstage + 64) * 512 + cstage, Al_ + 2048 + wv * 512); \
    }

#define DO_MFMA(BUF)                                                              \
    {                                                                             \
        const ushort_t* As_ = (const ushort_t*)Ab[BUF];                           \
        const ushort_t* Ss_ = (const ushort_t*)Sb[BUF];                           \
        bf16x8 af_[4], bf_[4];                                                    \
        _Pragma("unroll")                                                         \
        for (int i_ = 0; i_ < 4; ++i_)                                            \
            af_[i_] = *(const bf16x8*)&As_[(wm * 64 + i_ * 16 + m16) * 32 + quad * 8]; \
        _Pragma("unroll")                                                         \
        for (int j_ = 0; j_ < 4; ++j_)                                            \
            bf_[j_] = *(const bf16x8*)&Ss_[(wn * 64 + j_ * 16 + m16) * 32 + quad * 8]; \
        _Pragma("unroll")                                                         \
        for (int i_ = 0; i_ < 4; ++i_) {                                          \
            _Pragma("unroll")                                                     \
            for (int j_ = 0; j_ < 4; ++j_)                                        \
                acc[i_][j_] = __builtin_amdgcn_mfma_f32_16x16x32_bf16(af_[i_], bf_[j_], acc[i_][j_], 0, 0, 0); \
        }                                                                         \
    }

    // ---------- prologue: stage XT(0), S(0), A(0) ----------
    STAGE_XT(0);
    __syncthreads();                 // XT(0) + params visible
    COMPUTE_S(0, 0);
    ISSUE_DMA(0, 0, 0);
    __syncthreads();                 // S(0)/A(0) ready (barrier drains vmcnt)

    // ---------- main pipelined loop: t = 0..110, prepare t+1 ----------
    for (int t = 0; t < 111; ++t) {
        const int buf = t & 1;
        const int tn  = t + 1;
        const int kn  = tn % 7;
        const int ccn = tn / 7;

        ISSUE_DMA(kn, ccn, buf ^ 1);     // A(t+1): dest buffer's readers done pre-barrier
        DO_MFMA(buf);                    // frag reads + 16 independent MFMAs fill matrix pipe

        if (kn == 0) {                   // cc boundary: re-stage XT behind the MFMAs
            STAGE_XT(ccn);
            __syncthreads();             // XT(ccn) visible before gathers
        }
        COMPUTE_S(kn, buf ^ 1);          // interp VALU+LDS overlaps matrix pipe
        __syncthreads();                 // step fence: S/A(t+1) ready, frag reads(t) done
    }

    // ---------- final step ----------
    DO_MFMA(1);                          // t=111 -> buf = 111&1 = 1

    // ---------- epilogue (verified C/D layout) ----------
    #pragma unroll
    for (int i = 0; i < 4; ++i) {
        const int dd = d0 + wm * 64 + i * 16 + quad * 4;
        float bv[4];
        #pragma unroll
        for (int r = 0; r < 4; ++r) bv[r] = bias[dd + r];
        #pragma unroll
        for (int j = 0; j < 4; ++j) {
            const int oo = o0 + wn * 64 + j * 16 + m16;
            if (oo < OUT_LEN) {
                float* op = out + (size_t)b * COUT * OUT_LEN + (size_t)dd * OUT_LEN + oo;
                #pragma unroll
                for (int r = 0; r < 4; ++r)
                    op[(size_t)r * OUT_LEN] = acc[i][j][r] + bv[r];
            }
        }
    }
#undef STAGE_XT
#undef COMPUTE_S
#undef ISSUE_DMA
#undef DO_MFMA
}

// ---------------- fallback (round-1 fp32 kernel, used only if ws too small) ----------------
#define BM 64
#define BN 64
#define BC 8
#define TT (BC * K_)

__global__ __launch_bounds__(256, 2)
void deform_conv1d_fallback(const float* __restrict__ x, const float* __restrict__ offsets,
                            const float* __restrict__ weight, const float* __restrict__ bias,
                            float* __restrict__ out) {
    const int o0 = blockIdx.x * BN, d0 = blockIdx.y * BM, b = blockIdx.z, tid = threadIdx.x;
    __shared__ int   SU[BN * K_];
    __shared__ float SG0[BN * K_], SG1[BN * K_];
    __shared__ float XT[BC][BN + 8];
    __shared__ float S[BC][K_][BN];
    __shared__ float WT[BM][TT + 1];
    for (int e = tid; e < BN * K_; e += 256) {
        const int ol = e / K_, k = e % K_, o = o0 + ol;
        int u0rel = 0; float g0 = 0.f, g1 = 0.f;
        if (o < OUT_LEN) {
            const float t0 = (float)o;
            const float off = offsets[(size_t)b * OUT_LEN * K_ + (size_t)o * K_ + k];
            float T = fminf(fmaxf(t0 + (float)k + off, t0), t0 + 6.0f);
            int u0 = (int)floorf(T); if (u0 > L_ - 2) u0 = L_ - 2;
            g0 = fmaxf(1.0f - fabsf((float)u0 - T), 0.0f);
            g1 = fmaxf(1.0f - fabsf((float)(u0 + 1) - T), 0.0f);
            u0rel = u0 - o0;
        }
        SU[e] = u0rel; SG0[e] = g0; SG1[e] = g1;
    }
    float acc[4][4];
    #pragma unroll
    for (int i = 0; i < 4; ++i) {
        #pragma unroll
        for (int j = 0; j < 4; ++j) acc[i][j] = 0.f;
    }
    const int ty = tid >> 4, tx = tid & 15;
    const float* xb = x + (size_t)b * CIN * L_;
    for (int c0 = 0; c0 < CIN; c0 += BC) {
        __syncthreads();
        for (int e = tid; e < BC * (BN + 7); e += 256) {
            const int cl = e / (BN + 7), j = e % (BN + 7), pos = o0 + j;
            XT[cl][j] = (pos < L_) ? xb[(size_t)(c0 + cl) * L_ + pos] : 0.f;
        }
        for (int e = tid; e < BM * TT; e += 256) {
            const int d = e / TT, t = e % TT;
            WT[d][t] = weight[(size_t)(d0 + d) * (CIN * K_) + c0 * K_ + t];
        }
        __syncthreads();
        for (int e = tid; e < BC * K_ * BN; e += 256) {
            const int cl = e / (K_ * BN), r = e % (K_ * BN), k = r / BN, ol = r % BN;
            const int p = ol * K_ + k, u = SU[p];
            S[cl][k][ol] = SG0[p] * XT[cl][u] + SG1[p] * XT[cl][u + 1];
        }
        __syncthreads();
        #pragma unroll
        for (int t = 0; t < TT; ++t) {
            const int cl = t / K_, k = t % K_;
            const float4 s4 = *(const float4*)&S[cl][k][tx * 4];
            const float w0 = WT[ty * 4 + 0][t], w1 = WT[ty * 4 + 1][t];
            const float w2 = WT[ty * 4 + 2][t], w3 = WT[ty * 4 + 3][t];
            acc[0][0] += w0 * s4.x; acc[0][1] += w0 * s4.y; acc[0][2] += w0 * s4.z; acc[0][3] += w0 * s4.w;
            acc[1][0] += w1 * s4.x; acc[1][1] += w1 * s4.y; acc[1][2] += w1 * s4.z; acc[1][3] += w1 * s4.w;
            acc[2][0] += w2 * s4.x; acc[2][1] += w2 * s4.y; acc[2][2] += w2 * s4.z; acc[2][3] += w2 * s4.w;
            acc[3][0] += w3 * s4.x; acc[3][1] += w3 * s4.y; acc[3][2] += w3 * s4.z; acc[3][3] += w3 * s4.w;
        }
    }
    #pragma unroll
    for (int i = 0; i < 4; ++i) {
        const int d = d0 + ty * 4 + i;
        const float bvv = bias[d];
        #pragma unroll
        for (int j = 0; j < 4; ++j) {
            const int o = o0 + tx * 4 + j;
            if (o < OUT_LEN)
                out[(size_t)b * COUT * OUT_LEN + (size_t)d * OUT_LEN + o] = acc[i][j] + bvv;
        }
    }
}

extern "C" void kernel_launch(void* const* d_in, const int* in_sizes, int n_in,
                              void* d_out, int out_size, void* d_ws, size_t ws_size,
                              hipStream_t stream) {
    const float* x       = (const float*)d_in[0];
    const float* offsets = (const float*)d_in[1];
    const float* weight  = (const float*)d_in[2];
    const float* bias    = (const float*)d_in[3];
    float* out = (float*)d_out;

    const size_t WR_BYTES = (size_t)512 * 512 * 7 * 2;

    if (ws_size < WR_BYTES) {
        dim3 grid((OUT_LEN + BN - 1) / BN, COUT / BM, B_);
        deform_conv1d_fallback<<<grid, 256, 0, stream>>>(x, offsets, weight, bias, out);
        return;
    }

    uint32_t* Wr_u32 = (uint32_t*)d_ws;
    ushort_t* Wr     = (ushort_t*)d_ws;

    reorder_w_kernel<<<3584, 256, 0, stream>>>(weight, Wr_u32);
    fused_kernel<<<dim3(32, 4, B_), 256, 0, stream>>>(x, offsets, Wr, bias, out);
}

// Round 6
// 220.352 us; speedup vs baseline: 1.1601x; 1.1601x over previous
//
#include <hip/hip_runtime.h>
#include <hip/hip_bf16.h>
#include <stdint.h>

#define B_      4
#define CIN     512
#define COUT    512
#define L_      4096
#define K_      7
#define OUT_LEN 4090

typedef unsigned short ushort_t;
typedef __attribute__((ext_vector_type(8))) __bf16 bf16x8;
typedef __attribute__((ext_vector_type(4))) float f32x4;

__device__ __forceinline__ uint32_t f2bf(float f) {
    uint32_t u = __float_as_uint(f);
    return (u + 0x7fffu + ((u >> 16) & 1u)) >> 16;
}

__device__ __forceinline__ uint32_t pack2bf(float s0, float s1) {   // s0 -> low 16
    __hip_bfloat162 h = __float22bfloat162_rn(make_float2(s0, s1));
    uint32_t r;
    __builtin_memcpy(&r, &h, 4);
    return r;
}

__device__ __forceinline__ void async16(const void* g, void* l) {
    __builtin_amdgcn_global_load_lds(
        (const __attribute__((address_space(1))) unsigned int*)g,
        (__attribute__((address_space(3))) unsigned int*)l, 16, 0, 0);
}

// ---------------- kernel 1: weight reorder+cast: Wr[k][d][c] bf16 ----------------
__global__ __launch_bounds__(256)
void reorder_w_kernel(const float* __restrict__ w, uint32_t* __restrict__ Wr) {
    const int e     = blockIdx.x * 256 + threadIdx.x;
    const int cpair = e & 255;
    const int rest  = e >> 8;
    const int d     = rest & 511;
    const int k     = rest >> 9;
    const int c     = cpair * 2;
    const float w0 = w[(size_t)d * 3584 + (size_t)c * 7 + k];
    const float w1 = w[(size_t)d * 3584 + (size_t)(c + 1) * 7 + k];
    Wr[((size_t)(k * 512 + d) << 8) + cpair] = (f2bf(w1) << 16) | f2bf(w0);
}

// ---------------- kernel 2: fused interp + bf16 MFMA GEMM ----------------
// grid (32, 4, 4), 256 threads (4 waves); 112 K-steps of 32 channels
__global__ __launch_bounds__(256)
void fused_kernel(const float* __restrict__ x, const float* __restrict__ offs,
                  const ushort_t* __restrict__ Wr, const float* __restrict__ bias,
                  float* __restrict__ out) {
    const int o0   = blockIdx.x * 128;
    const int d0   = blockIdx.y * 128;
    const int b    = blockIdx.z;
    const int tid  = threadIdx.x;
    const int wv   = tid >> 6;
    const int lane = tid & 63;
    const int m16  = lane & 15;
    const int quad = lane >> 4;
    const int wm   = wv >> 1;
    const int wn   = wv & 1;

    // XTB[col][cp^swz]: packed bf16 pair (c=2cp low, c=2cp+1 high), swz = (col>>1)&15
    __shared__ uint32_t XTB[136 * 16];                           // 8704 B
    __shared__ __align__(16) uint32_t Sb0[2048], Sb1[2048];      // B-tile bufs
    __shared__ __align__(16) uint32_t Ab0[2048], Ab1[2048];      // A-tile bufs
    __shared__ int      SU[896];
    __shared__ float2   PG[896];

    // ---- interp params ----
    for (int e = tid; e < 896; e += 256) {
        const int k  = e >> 7;
        const int ol = e & 127;
        int o = o0 + ol; if (o > OUT_LEN - 1) o = OUT_LEN - 1;
        const float t0  = (float)o;
        const float off = offs[((size_t)b * OUT_LEN + o) * K_ + k];
        float T = t0 + (float)k + off;
        T = fmaxf(T, t0);
        T = fminf(T, t0 + 6.0f);
        int u0 = (int)floorf(T);
        if (u0 > L_ - 2) u0 = L_ - 2;
        const float g0 = fmaxf(1.0f - fabsf((float)u0 - T), 0.0f);
        const float g1 = fmaxf(1.0f - fabsf((float)(u0 + 1) - T), 0.0f);
        SU[e] = u0 - o0;
        PG[e] = make_float2(g0, g1);
    }

    f32x4 acc[4][4];
    #pragma unroll
    for (int i = 0; i < 4; ++i) {
        #pragma unroll
        for (int j = 0; j < 4; ++j) acc[i][j] = (f32x4){0.f, 0.f, 0.f, 0.f};
    }

    const int dstage = tid >> 2;
    const int cstage = (tid & 3) * 8;
    const int olr    = tid >> 1;
    const int half   = tid & 1;

    const float* xb = x + (size_t)b * CIN * L_ + o0;

#define STAGE_XT(CC)                                                              \
    {                                                                             \
        const float* xc_ = xb + (size_t)(CC) * 32 * L_;                           \
        _Pragma("unroll")                                                         \
        for (int r_ = 0; r_ < 3; ++r_) {                                          \
            const int e_ = r_ * 256 + tid;                                        \
            if (e_ < 544) {                                                       \
                const int cp_   = e_ / 34;                                        \
                const int col4_ = e_ - cp_ * 34;                                  \
                const int colb_ = col4_ * 4;                                      \
                const float* p0_ = xc_ + (size_t)(2 * cp_) * L_ + colb_;          \
                const float* p1_ = p0_ + L_;                                      \
                float4 v0_, v1_;                                                  \
                if (o0 + colb_ + 3 < L_) {                                        \
                    v0_ = *(const float4*)p0_;                                    \
                    v1_ = *(const float4*)p1_;                                    \
                } else {                                                          \
                    float a0_ = (o0 + colb_ + 0 < L_) ? p0_[0] : 0.f;             \
                    float a1_ = (o0 + colb_ + 1 < L_) ? p0_[1] : 0.f;             \
                    float a2_ = (o0 + colb_ + 2 < L_) ? p0_[2] : 0.f;             \
                    float a3_ = (o0 + colb_ + 3 < L_) ? p0_[3] : 0.f;             \
                    float b0_ = (o0 + colb_ + 0 < L_) ? p1_[0] : 0.f;             \
                    float b1_ = (o0 + colb_ + 1 < L_) ? p1_[1] : 0.f;             \
                    float b2_ = (o0 + colb_ + 2 < L_) ? p1_[2] : 0.f;             \
                    float b3_ = (o0 + colb_ + 3 < L_) ? p1_[3] : 0.f;             \
                    v0_ = make_float4(a0_, a1_, a2_, a3_);                        \
                    v1_ = make_float4(b0_, b1_, b2_, b3_);                        \
                }                                                                 \
                const float* f0_ = (const float*)&v0_;                            \
                const float* f1_ = (const float*)&v1_;                            \
                _Pragma("unroll")                                                 \
                for (int ii_ = 0; ii_ < 4; ++ii_) {                               \
                    const int col_ = colb_ + ii_;                                 \
                    XTB[col_ * 16 + (cp_ ^ ((col_ >> 1) & 15))] =                 \
                        pack2bf(f0_[ii_], f1_[ii_]);                              \
                }                                                                 \
            }                                                                     \
        }                                                                         \
    }

#define COMPUTE_S(KN, SW)                                                         \
    {                                                                             \
        const int row_ = ((KN) << 7) | olr;                                       \
        const int u_   = SU[row_];                                                \
        const float2 g_ = PG[row_];                                               \
        const uint32_t* X0_ = &XTB[u_ * 16];                                      \
        const uint32_t* X1_ = &XTB[(u_ + 1) * 16];                                \
        const int s0_ = (u_ >> 1) & 15;                                           \
        const int s1_ = ((u_ + 1) >> 1) & 15;                                     \
        uint32_t r_[8];                                                           \
        _Pragma("unroll")                                                         \
        for (int j_ = 0; j_ < 8; ++j_) {                                          \
            const int cp_ = half * 8 + j_;                                        \
            const uint32_t wl_ = X0_[cp_ ^ s0_];                                  \
            const uint32_t wh_ = X1_[cp_ ^ s1_];                                  \
            const float l0_ = __uint_as_float(wl_ << 16);                         \
            const float l1_ = __uint_as_float(wl_ & 0xffff0000u);                 \
            const float h0_ = __uint_as_float(wh_ << 16);                         \
            const float h1_ = __uint_as_float(wh_ & 0xffff0000u);                 \
            r_[j_] = pack2bf(g_.x * l0_ + g_.y * h0_, g_.x * l1_ + g_.y * h1_);   \
        }                                                                         \
        uint32_t* Sw_ = &(SW)[olr * 16 + half * 8];                               \
        *(uint4*)(Sw_ + 0) = make_uint4(r_[0], r_[1], r_[2], r_[3]);              \
        *(uint4*)(Sw_ + 4) = make_uint4(r_[4], r_[5], r_[6], r_[7]);              \
    }

#define ISSUE_DMA(KN, CCN, AW)                                                    \
    {                                                                             \
        const ushort_t* Wk_ = Wr + (size_t)((KN) * 512 + d0) * 512 + (CCN) * 32;  \
        ushort_t* Al_ = (ushort_t*)(AW);                                          \
        async16(Wk_ + (size_t)dstage * 512 + cstage,        Al_ + wv * 512);      \
        async16(Wk_ + (size_t)(dstage + 64) * 512 + cstage, Al_ + 2048 + wv * 512); \
    }

// one K-step: reads frags (AR,SR), prefetches t+1 into (AW,SW); statically
// distinct arrays -> compiler proves no alias between DMA write and ds_reads
#define STEP(AR, SR, AW, SW)                                                      \
    {                                                                             \
        const ushort_t* As_ = (const ushort_t*)(AR);                              \
        const ushort_t* Ss_ = (const ushort_t*)(SR);                              \
        bf16x8 af_[4], bfr_[4];                                                   \
        _Pragma("unroll")                                                         \
        for (int i_ = 0; i_ < 4; ++i_)                                            \
            af_[i_] = *(const bf16x8*)&As_[(wm * 64 + i_ * 16 + m16) * 32 + quad * 8]; \
        _Pragma("unroll")                                                         \
        for (int j_ = 0; j_ < 4; ++j_)                                            \
            bfr_[j_] = *(const bf16x8*)&Ss_[(wn * 64 + j_ * 16 + m16) * 32 + quad * 8]; \
        int kn_ = kc + 1, ccn_ = ccc;                                             \
        if (kn_ == 7) { kn_ = 0; ++ccn_; }                                        \
        const bool last_ = (ccn_ == 16);                                          \
        if (!last_) { ISSUE_DMA(kn_, ccn_, AW); }                                 \
        _Pragma("unroll")                                                         \
        for (int i_ = 0; i_ < 4; ++i_) {                                          \
            _Pragma("unroll")                                                     \
            for (int j_ = 0; j_ < 4; ++j_)                                        \
                acc[i_][j_] = __builtin_amdgcn_mfma_f32_16x16x32_bf16(af_[i_], bfr_[j_], acc[i_][j_], 0, 0, 0); \
        }                                                                         \
        if (!last_) {                                                             \
            if (kn_ == 0) { STAGE_XT(ccn_); __syncthreads(); }                    \
            COMPUTE_S(kn_, SW);                                                   \
        }                                                                         \
        __syncthreads();                                                          \
        kc = kn_; ccc = ccn_;                                                     \
    }

    // ---------- prologue ----------
    STAGE_XT(0);
    __syncthreads();                 // params + XTB(0) visible
    COMPUTE_S(0, Sb0);
    ISSUE_DMA(0, 0, Ab0);
    __syncthreads();                 // S(0)/A(0) ready (barrier drains vmcnt)

    int kc = 0, ccc = 0;
    for (int tp = 0; tp < 56; ++tp) {
        STEP(Ab0, Sb0, Ab1, Sb1);
        STEP(Ab1, Sb1, Ab0, Sb0);
    }

    // ---------- epilogue (verified C/D layout) ----------
    #pragma unroll
    for (int i = 0; i < 4; ++i) {
        const int dd = d0 + wm * 64 + i * 16 + quad * 4;
        float bv[4];
        #pragma unroll
        for (int r = 0; r < 4; ++r) bv[r] = bias[dd + r];
        #pragma unroll
        for (int j = 0; j < 4; ++j) {
            const int oo = o0 + wn * 64 + j * 16 + m16;
            if (oo < OUT_LEN) {
                float* op = out + (size_t)b * COUT * OUT_LEN + (size_t)dd * OUT_LEN + oo;
                #pragma unroll
                for (int r = 0; r < 4; ++r)
                    op[(size_t)r * OUT_LEN] = acc[i][j][r] + bv[r];
            }
        }
    }
#undef STAGE_XT
#undef COMPUTE_S
#undef ISSUE_DMA
#undef STEP
}

// ---------------- fallback (round-1 fp32 kernel, used only if ws too small) ----------------
#define BM 64
#define BN 64
#define BC 8
#define TT (BC * K_)

__global__ __launch_bounds__(256, 2)
void deform_conv1d_fallback(const float* __restrict__ x, const float* __restrict__ offsets,
                            const float* __restrict__ weight, const float* __restrict__ bias,
                            float* __restrict__ out) {
    const int o0 = blockIdx.x * BN, d0 = blockIdx.y * BM, b = blockIdx.z, tid = threadIdx.x;
    __shared__ int   SU[BN * K_];
    __shared__ float SG0[BN * K_], SG1[BN * K_];
    __shared__ float XT[BC][BN + 8];
    __shared__ float S[BC][K_][BN];
    __shared__ float WT[BM][TT + 1];
    for (int e = tid; e < BN * K_; e += 256) {
        const int ol = e / K_, k = e % K_, o = o0 + ol;
        int u0rel = 0; float g0 = 0.f, g1 = 0.f;
        if (o < OUT_LEN) {
            const float t0 = (float)o;
            const float off = offsets[(size_t)b * OUT_LEN * K_ + (size_t)o * K_ + k];
            float T = fminf(fmaxf(t0 + (float)k + off, t0), t0 + 6.0f);
            int u0 = (int)floorf(T); if (u0 > L_ - 2) u0 = L_ - 2;
            g0 = fmaxf(1.0f - fabsf((float)u0 - T), 0.0f);
            g1 = fmaxf(1.0f - fabsf((float)(u0 + 1) - T), 0.0f);
            u0rel = u0 - o0;
        }
        SU[e] = u0rel; SG0[e] = g0; SG1[e] = g1;
    }
    float acc[4][4];
    #pragma unroll
    for (int i = 0; i < 4; ++i) {
        #pragma unroll
        for (int j = 0; j < 4; ++j) acc[i][j] = 0.f;
    }
    const int ty = tid >> 4, tx = tid & 15;
    const float* xb = x + (size_t)b * CIN * L_;
    for (int c0 = 0; c0 < CIN; c0 += BC) {
        __syncthreads();
        for (int e = tid; e < BC * (BN + 7); e += 256) {
            const int cl = e / (BN + 7), j = e % (BN + 7), pos = o0 + j;
            XT[cl][j] = (pos < L_) ? xb[(size_t)(c0 + cl) * L_ + pos] : 0.f;
        }
        for (int e = tid; e < BM * TT; e += 256) {
            const int d = e / TT, t = e % TT;
            WT[d][t] = weight[(size_t)(d0 + d) * (CIN * K_) + c0 * K_ + t];
        }
        __syncthreads();
        for (int e = tid; e < BC * K_ * BN; e += 256) {
            const int cl = e / (K_ * BN), r = e % (K_ * BN), k = r / BN, ol = r % BN;
            const int p = ol * K_ + k, u = SU[p];
            S[cl][k][ol] = SG0[p] * XT[cl][u] + SG1[p] * XT[cl][u + 1];
        }
        __syncthreads();
        #pragma unroll
        for (int t = 0; t < TT; ++t) {
            const int cl = t / K_, k = t % K_;
            const float4 s4 = *(const float4*)&S[cl][k][tx * 4];
            const float w0 = WT[ty * 4 + 0][t], w1 = WT[ty * 4 + 1][t];
            const float w2 = WT[ty * 4 + 2][t], w3 = WT[ty * 4 + 3][t];
            acc[0][0] += w0 * s4.x; acc[0][1] += w0 * s4.y; acc[0][2] += w0 * s4.z; acc[0][3] += w0 * s4.w;
            acc[1][0] += w1 * s4.x; acc[1][1] += w1 * s4.y; acc[1][2] += w1 * s4.z; acc[1][3] += w1 * s4.w;
            acc[2][0] += w2 * s4.x; acc[2][1] += w2 * s4.y; acc[2][2] += w2 * s4.z; acc[2][3] += w2 * s4.w;
            acc[3][0] += w3 * s4.x; acc[3][1] += w3 * s4.y; acc[3][2] += w3 * s4.z; acc[3][3] += w3 * s4.w;
        }
    }
    #pragma unroll
    for (int i = 0; i < 4; ++i) {
        const int d = d0 + ty * 4 + i;
        const float bvv = bias[d];
        #pragma unroll
        for (int j = 0; j < 4; ++j) {
            const int o = o0 + tx * 4 + j;
            if (o < OUT_LEN)
                out[(size_t)b * COUT * OUT_LEN + (size_t)d * OUT_LEN + o] = acc[i][j] + bvv;
        }
    }
}

extern "C" void kernel_launch(void* const* d_in, const int* in_sizes, int n_in,
                              void* d_out, int out_size, void* d_ws, size_t ws_size,
                              hipStream_t stream) {
    const float* x       = (const float*)d_in[0];
    const float* offsets = (const float*)d_in[1];
    const float* weight  = (const float*)d_in[2];
    const float* bias    = (const float*)d_in[3];
    float* out = (float*)d_out;

    const size_t WR_BYTES = (size_t)512 * 512 * 7 * 2;

    if (ws_size < WR_BYTES) {
        dim3 grid((OUT_LEN + BN - 1) / BN, COUT / BM, B_);
        deform_conv1d_fallback<<<grid, 256, 0, stream>>>(x, offsets, weight, bias, out);
        return;
    }

    uint32_t* Wr_u32 = (uint32_t*)d_ws;
    ushort_t* Wr     = (ushort_t*)d_ws;

    reorder_w_kernel<<<3584, 256, 0, stream>>>(weight, Wr_u32);
    fused_kernel<<<dim3(32, 4, B_), 256, 0, stream>>>(x, offsets, Wr, bias, out);
}